// Round 1
// baseline (529.339 us; speedup 1.0000x reference)
//
#include <hip/hip_runtime.h>

// DotProcessorBlock: feat = x*w + b (B=4096, N=256); out[b, :] = first
// n(n+1)/2 = 32896 row-major entries of feat ⊗ feat.
// 32896 = 128 full rows of 256 + 128 entries of row 128.
// Pure HBM-write-bound: 539 MB out vs 4 MB in.

#define NFEAT 256
#define NOUT  32896   // 256*257/2
#define NOUT4 8224    // NOUT / 4

__global__ __launch_bounds__(256) void dot_outer_kernel(
    const float* __restrict__ x,
    const float* __restrict__ w,
    const float* __restrict__ bias,
    float* __restrict__ out)
{
    __shared__ float feat[NFEAT];
    const int b = blockIdx.x;
    const int t = threadIdx.x;

    // feat = x*w + b  (coalesced: lane t loads element t)
    feat[t] = x[(size_t)b * NFEAT + t] * w[t] + bias[t];
    __syncthreads();

    const float4* feat4 = (const float4*)feat;
    float4* out4 = (float4*)(out + (size_t)b * NOUT);

    // Main body: 32 iterations x 256 threads = 8192 float4 stores
    // covering rows i = 0..127 (each 64-lane wave handles one full row:
    // feat[i] is a wave-uniform LDS broadcast, feat4[j4] a b128 read).
    #pragma unroll
    for (int iter = 0; iter < 32; ++iter) {
        const int idx = iter * 256 + t;      // float4 index within batch
        const int i  = idx >> 6;             // row 0..127
        const int j4 = idx & 63;             // float4 col 0..63
        const float  fi = feat[i];
        const float4 fj = feat4[j4];
        float4 v;
        v.x = fi * fj.x;
        v.y = fi * fj.y;
        v.z = fi * fj.z;
        v.w = fi * fj.w;
        out4[idx] = v;
    }

    // Tail: row 128, cols 0..127 -> 32 float4 stores
    if (t < 32) {
        const float  fi = feat[128];
        const float4 fj = feat4[t];
        float4 v;
        v.x = fi * fj.x;
        v.y = fi * fj.y;
        v.z = fi * fj.z;
        v.w = fi * fj.w;
        out4[8192 + t] = v;
    }
}

extern "C" void kernel_launch(void* const* d_in, const int* in_sizes, int n_in,
                              void* d_out, int out_size, void* d_ws, size_t ws_size,
                              hipStream_t stream) {
    const float* x    = (const float*)d_in[0];
    const float* w    = (const float*)d_in[1];
    const float* bias = (const float*)d_in[2];
    float* out = (float*)d_out;

    const int B = in_sizes[0] / NFEAT;   // 4096
    dot_outer_kernel<<<B, 256, 0, stream>>>(x, w, bias, out);
}